// Round 12
// baseline (86.149 us; speedup 1.0000x reference)
//
#include <hip/hip_runtime.h>

// SSIM loss v11: TH=4 straight-line waves. Each wave: load 7 row-pairs
// (staggered), two fully-unrolled COMPUTE bodies (static ring slots 0..5 /
// 1..6 -- no shifts, no loop), DPP halo, SGPR-resident weights, pkrtz packs.

namespace {
constexpr int W = 320, H = 320, B = 128;
constexpr int TH = 4;
constexpr int NSTRIPE = H / TH;     // 80
constexpr int WPB = 4;              // waves per block
constexpr int NWAVE = B * NSTRIPE;  // 10240
constexpr int NBLK = NWAVE / WPB;   // 2560
constexpr float C1 = 1.0e-4f;
constexpr float C2 = 9.0e-4f;
constexpr int NSLOT = 128;
constexpr int SSTR = 16;
}

typedef _Float16 h2 __attribute__((ext_vector_type(2)));

__device__ __forceinline__ float fdot2f(h2 a, h2 b, float c) {
#if __has_builtin(__builtin_amdgcn_fdot2)
  return __builtin_amdgcn_fdot2(a, b, c, false);
#else
  return fmaf((float)a.x, (float)b.x, fmaf((float)a.y, (float)b.y, c));
#endif
}

__device__ __forceinline__ float rcpf(float x) {
  float r;
  asm("v_rcp_f32 %0, %1" : "=v"(r) : "v"(x));
  return r;
}

__device__ __forceinline__ h2 pack2(float a, float b) {
  return h2{(_Float16)a, (_Float16)b};
}

__device__ __forceinline__ h2 pkrtz(float a, float b) {
#if __has_builtin(__builtin_amdgcn_cvt_pkrtz)
  return __builtin_bit_cast(h2, __builtin_amdgcn_cvt_pkrtz(a, b));
#else
  return pack2(a, b);
#endif
}

// Force a wave-uniform h2 into an SGPR (VOP3P may take 1 SGPR operand).
__device__ __forceinline__ h2 sgh2(h2 v) {
  return __builtin_bit_cast(
      h2, __builtin_amdgcn_readfirstlane(__builtin_bit_cast(int, v)));
}

// lane i <- lane i-1, lane 0 <- 0 (wave_shr:1, bound_ctrl). [HW-verified v7/v8]
__device__ __forceinline__ h2 dpp_up1(h2 v) {
  int r = __builtin_amdgcn_update_dpp(0, __builtin_bit_cast(int, v),
                                      0x138, 0xF, 0xF, true);
  return __builtin_bit_cast(h2, r);
}
// lane i <- lane i+1, lane 63 <- 0 (wave_shl:1, bound_ctrl). [HW-verified v7/v8]
__device__ __forceinline__ h2 dpp_dn1(h2 v) {
  int r = __builtin_amdgcn_update_dpp(0, __builtin_bit_cast(int, v),
                                      0x130, 0xF, 0xF, true);
  return __builtin_bit_cast(h2, r);
}

#define LOADP_RAW(ROW, A0, B0, A1, B1)                                        \
  do {                                                                        \
    const int r0_ = (ROW);                                                    \
    if (r0_ >= 0 && r0_ < H) {                                                \
      const float* p_ = P + r0_ * W;                                          \
      const float* t_ = T + r0_ * W;                                          \
      _Pragma("unroll") for (int c_ = 0; c_ < 5; ++c_) {                      \
        A0[c_] = p_[c_]; B0[c_] = t_[c_];                                     \
      }                                                                       \
    } else {                                                                  \
      _Pragma("unroll") for (int c_ = 0; c_ < 5; ++c_) {                      \
        A0[c_] = 0.f; B0[c_] = 0.f;                                           \
      }                                                                       \
    }                                                                         \
    if (r0_ + 1 >= 0 && r0_ + 1 < H) {                                        \
      const float* p_ = P + (r0_ + 1) * W;                                    \
      const float* t_ = T + (r0_ + 1) * W;                                    \
      _Pragma("unroll") for (int c_ = 0; c_ < 5; ++c_) {                      \
        A1[c_] = p_[c_]; B1[c_] = t_[c_];                                     \
      }                                                                       \
    } else {                                                                  \
      _Pragma("unroll") for (int c_ = 0; c_ < 5; ++c_) {                      \
        A1[c_] = 0.f; B1[c_] = 0.f;                                           \
      }                                                                       \
    }                                                                         \
  } while (0)

#define PACKTO(J, A0, B0, A1, B1)                                             \
  do {                                                                        \
    _Pragma("unroll") for (int c_ = 0; c_ < 5; ++c_) {                        \
      rp[J][c_] = pkrtz(A0[c_], A1[c_]);                                      \
      rt[J][c_] = pkrtz(B0[c_], B1[c_]);                                      \
    }                                                                         \
  } while (0)

#define HALO(PKc, L, R)                                                       \
  do {                                                                        \
    _Pragma("unroll") for (int c_ = 0; c_ < 5; ++c_) {                        \
      L[c_] = dpp_up1(PKc[c_]);                                               \
      R[c_] = dpp_dn1(PKc[c_]);                                               \
    }                                                                         \
  } while (0)

#define HBLUR(PKc, L, R, O)                                                   \
  do {                                                                        \
    _Pragma("unroll") for (int c_ = 0; c_ < 5; ++c_) {                        \
      h2 s1_ = WH[0] * ((c_ + 0 < 5) ? L[c_] : PKc[c_ - 5]);                  \
      _Pragma("unroll") for (int k_ = 1; k_ < 5; ++k_) {                      \
        const int i_ = c_ + k_;                                               \
        s1_ = WH[k_] * ((i_ < 5) ? L[i_] : PKc[i_ - 5]) + s1_;                \
      }                                                                       \
      h2 s2_ = WH[10] * R[c_];                                                \
      _Pragma("unroll") for (int k_ = 9; k_ >= 5; --k_) {                     \
        const int i_ = c_ + k_;                                               \
        s2_ = WH[k_] * ((i_ < 10) ? PKc[i_ - 5] : R[i_ - 10]) + s2_;          \
      }                                                                       \
      O[c_] = s1_ + s2_;                                                      \
    }                                                                         \
  } while (0)

// One output-row-pair; ring window = slots I..I+5 (static indices).
#define COMPUTE(I)                                                            \
  do {                                                                        \
    h2 PK[5][5];                                                              \
    _Pragma("unroll") for (int c = 0; c < 5; ++c) {                           \
      float mpA = 0, mtA = 0, ppA = 0, ttA = 0, ptA = 0;                      \
      float mpB = 0, mtB = 0, ppB = 0, ttB = 0, ptB = 0;                      \
      _Pragma("unroll") for (int j = 0; j < 6; ++j) {                         \
        const h2 a = rp[(I) + j][c], b = rt[(I) + j][c];                      \
        const h2 aa = a * a, bb = b * b, ab = a * b;                          \
        const h2 wa = wAv[j], wb = wBv[j];                                    \
        mpA = fdot2f(wa, a, mpA);                                             \
        mtA = fdot2f(wa, b, mtA);                                             \
        ppA = fdot2f(wa, aa, ppA);                                            \
        ttA = fdot2f(wa, bb, ttA);                                            \
        ptA = fdot2f(wa, ab, ptA);                                            \
        mpB = fdot2f(wb, a, mpB);                                             \
        mtB = fdot2f(wb, b, mtB);                                             \
        ppB = fdot2f(wb, aa, ppB);                                            \
        ttB = fdot2f(wb, bb, ttB);                                            \
        ptB = fdot2f(wb, ab, ptB);                                            \
      }                                                                       \
      PK[0][c] = pkrtz(mpA, mpB);                                             \
      PK[1][c] = pkrtz(mtA, mtB);                                             \
      PK[2][c] = pkrtz(ppA, ppB);                                             \
      PK[3][c] = pkrtz(ttA, ttB);                                             \
      PK[4][c] = pkrtz(ptA, ptB);                                             \
    }                                                                         \
    h2 OUT[5][5];                                                             \
    _Pragma("unroll") for (int ch = 0; ch < 5; ++ch) {                        \
      h2 L[5], R[5];                                                          \
      HALO(PK[ch], L, R);                                                     \
      HBLUR(PK[ch], L, R, OUT[ch]);                                           \
    }                                                                         \
    _Pragma("unroll") for (int c = 0; c < 5; ++c) {                           \
      _Pragma("unroll") for (int r = 0; r < 2; ++r) {                         \
        const float mx = r ? (float)OUT[0][c].y : (float)OUT[0][c].x;         \
        const float my = r ? (float)OUT[1][c].y : (float)OUT[1][c].x;         \
        const float xx = r ? (float)OUT[2][c].y : (float)OUT[2][c].x;         \
        const float yy = r ? (float)OUT[3][c].y : (float)OUT[3][c].x;         \
        const float xy = r ? (float)OUT[4][c].y : (float)OUT[4][c].x;         \
        const float mxx = mx * mx, myy = my * my, mxy = mx * my;              \
        const float vx = xx - mxx, vy = yy - myy, vxy = xy - mxy;             \
        const float num = fmaf(2.f, mxy, C1) * fmaf(2.f, vxy, C2);            \
        const float den = (mxx + myy + C1) * (vx + vy + C2);                  \
        acc = fmaf(num, rcpf(den), acc);                                      \
      }                                                                       \
    }                                                                         \
  } while (0)

__global__ __launch_bounds__(256, 4) void ssim_main(
    const float* __restrict__ pred, const float* __restrict__ targ,
    float* __restrict__ sink, int slotmask, int sstr) {
  const int lane = threadIdx.x & 63;
  const int wid  = threadIdx.x >> 6;
  const int stripe = blockIdx.x * WPB + wid;
  const int img = stripe / NSTRIPE;
  const int y0  = (stripe % NSTRIPE) * TH;

  const float* __restrict__ P = pred + (size_t)img * (W * H) + 5 * lane;
  const float* __restrict__ T = targ + (size_t)img * (W * H) + 5 * lane;

  constexpr float WF[11] = {0.00102838f, 0.00759885f, 0.03600081f, 0.10936069f,
                            0.21300553f, 0.26601171f, 0.21300553f, 0.10936069f,
                            0.03600081f, 0.00759885f, 0.00102838f};
  // All weights wave-uniform -> force into SGPRs (1 SGPR operand per VOP3P ok).
  const h2 wAv[6] = {sgh2(pack2(WF[0], WF[1])),  sgh2(pack2(WF[2], WF[3])),
                     sgh2(pack2(WF[4], WF[5])),  sgh2(pack2(WF[6], WF[7])),
                     sgh2(pack2(WF[8], WF[9])),  sgh2(pack2(WF[10], 0.f))};
  const h2 wBv[6] = {sgh2(pack2(0.f, WF[0])),    sgh2(pack2(WF[1], WF[2])),
                     sgh2(pack2(WF[3], WF[4])),  sgh2(pack2(WF[5], WF[6])),
                     sgh2(pack2(WF[7], WF[8])),  sgh2(pack2(WF[9], WF[10]))};
  h2 WH[11];
#pragma unroll
  for (int k = 0; k < 11; ++k) WH[k] = sgh2(pack2(WF[k], WF[k]));

  // Ring: 7 row-pairs x 5 cols, (rowA,rowB) f16x2 per signal.
  h2 rp[7][5], rt[7][5];

  // Staggered preamble: 2 pairs in flight, pairs 0..6 -> slots 0..6.
  {
    float aA[5], bA[5], cA[5], dA[5];
    float aB[5], bB[5], cB[5], dB[5];
    LOADP_RAW(y0 - 5, aA, bA, cA, dA);   // pair0
    LOADP_RAW(y0 - 3, aB, bB, cB, dB);   // pair1
    PACKTO(0, aA, bA, cA, dA);
    LOADP_RAW(y0 - 1, aA, bA, cA, dA);   // pair2
    PACKTO(1, aB, bB, cB, dB);
    LOADP_RAW(y0 + 1, aB, bB, cB, dB);   // pair3
    PACKTO(2, aA, bA, cA, dA);
    LOADP_RAW(y0 + 3, aA, bA, cA, dA);   // pair4
    PACKTO(3, aB, bB, cB, dB);
    LOADP_RAW(y0 + 5, aB, bB, cB, dB);   // pair5
    PACKTO(4, aA, bA, cA, dA);
    LOADP_RAW(y0 + 7, aA, bA, cA, dA);   // pair6
    PACKTO(5, aB, bB, cB, dB);
    PACKTO(6, aA, bA, cA, dA);
  }

  float acc = 0.f;
  COMPUTE(0);   // output rows y0, y0+1   (ring slots 0..5)
  COMPUTE(1);   // output rows y0+2, y0+3 (ring slots 1..6)

  // ---- wave reduce + spread atomics ----
#pragma unroll
  for (int off = 32; off; off >>= 1) acc += __shfl_xor(acc, off, 64);
  if (lane == 0) atomicAdd(sink + (stripe & slotmask) * sstr, acc);
}

__global__ void ssim_final(const float* __restrict__ sink, int nslot, int sstr,
                           float* __restrict__ out) {
  const int tid = threadIdx.x;  // 64 threads
  float v = 0.f;
  for (int q = tid; q < nslot; q += 64) v += sink[q * sstr];
#pragma unroll
  for (int off = 32; off; off >>= 1) v += __shfl_xor(v, off, 64);
  if (tid == 0) out[0] = 1.f - v / 13107200.f;
}

extern "C" void kernel_launch(void* const* d_in, const int* in_sizes, int n_in,
                              void* d_out, int out_size, void* d_ws, size_t ws_size,
                              hipStream_t stream) {
  (void)in_sizes; (void)n_in; (void)out_size;
  const float* pred = (const float*)d_in[0];
  const float* targ = (const float*)d_in[1];
  float* out = (float*)d_out;

  float* sink;
  int nslot, sstr;
  const size_t need = (size_t)NSLOT * SSTR * sizeof(float);
  if (ws_size >= need) {
    sink = (float*)d_ws;
    nslot = NSLOT;
    sstr = SSTR;
  } else {
    sink = out;
    nslot = 1;
    sstr = 0;
  }
  (void)hipMemsetAsync(sink, 0, nslot == 1 ? sizeof(float) : need, stream);
  ssim_main<<<dim3(NBLK), dim3(256), 0, stream>>>(pred, targ, sink, nslot - 1, sstr);
  ssim_final<<<1, 64, 0, stream>>>(sink, nslot, sstr, out);
}

// Round 13
// 60.464 us; speedup vs baseline: 1.4248x; 1.4248x over previous
//
#include <hip/hip_runtime.h>

// SSIM loss v12: identical math/structure to v8 (best: 60.8us), single change:
// one wave per block (64 threads, 4096 blocks) for finer CU scheduling,
// better load balance, and smoother ramp/drain.

namespace {
constexpr int W = 320, H = 320, B = 128;
constexpr int TH = 10;
constexpr int NSTRIPE = H / TH;     // 32
constexpr int NWAVE = B * NSTRIPE;  // 4096
constexpr int ITERS = TH / 2;       // 5
constexpr float C1 = 1.0e-4f;
constexpr float C2 = 9.0e-4f;
constexpr int NSLOT = 128;
constexpr int SSTR = 16;
}

typedef _Float16 h2 __attribute__((ext_vector_type(2)));

__device__ __forceinline__ float fdot2f(h2 a, h2 b, float c) {
#if __has_builtin(__builtin_amdgcn_fdot2)
  return __builtin_amdgcn_fdot2(a, b, c, false);
#else
  return fmaf((float)a.x, (float)b.x, fmaf((float)a.y, (float)b.y, c));
#endif
}

__device__ __forceinline__ float rcpf(float x) {
  float r;
  asm("v_rcp_f32 %0, %1" : "=v"(r) : "v"(x));
  return r;
}

__device__ __forceinline__ h2 pack2(float a, float b) {
  return h2{(_Float16)a, (_Float16)b};
}

__device__ __forceinline__ h2 pkrtz(float a, float b) {
#if __has_builtin(__builtin_amdgcn_cvt_pkrtz)
  return __builtin_bit_cast(h2, __builtin_amdgcn_cvt_pkrtz(a, b));
#else
  return pack2(a, b);
#endif
}

// lane i <- lane i-1, lane 0 <- 0 (wave_shr:1, bound_ctrl). [HW-verified v7/v8]
__device__ __forceinline__ h2 dpp_up1(h2 v) {
  int r = __builtin_amdgcn_update_dpp(0, __builtin_bit_cast(int, v),
                                      0x138, 0xF, 0xF, true);
  return __builtin_bit_cast(h2, r);
}
// lane i <- lane i+1, lane 63 <- 0 (wave_shl:1, bound_ctrl). [HW-verified v7/v8]
__device__ __forceinline__ h2 dpp_dn1(h2 v) {
  int r = __builtin_amdgcn_update_dpp(0, __builtin_bit_cast(int, v),
                                      0x130, 0xF, 0xF, true);
  return __builtin_bit_cast(h2, r);
}

#define LOADP_RAW(ROW, A0, B0, A1, B1)                                        \
  do {                                                                        \
    const int r0_ = (ROW);                                                    \
    if (r0_ >= 0 && r0_ < H) {                                                \
      const float* p_ = P + r0_ * W;                                          \
      const float* t_ = T + r0_ * W;                                          \
      _Pragma("unroll") for (int c_ = 0; c_ < 5; ++c_) {                      \
        A0[c_] = p_[c_]; B0[c_] = t_[c_];                                     \
      }                                                                       \
    } else {                                                                  \
      _Pragma("unroll") for (int c_ = 0; c_ < 5; ++c_) {                      \
        A0[c_] = 0.f; B0[c_] = 0.f;                                           \
      }                                                                       \
    }                                                                         \
    if (r0_ + 1 >= 0 && r0_ + 1 < H) {                                        \
      const float* p_ = P + (r0_ + 1) * W;                                    \
      const float* t_ = T + (r0_ + 1) * W;                                    \
      _Pragma("unroll") for (int c_ = 0; c_ < 5; ++c_) {                      \
        A1[c_] = p_[c_]; B1[c_] = t_[c_];                                     \
      }                                                                       \
    } else {                                                                  \
      _Pragma("unroll") for (int c_ = 0; c_ < 5; ++c_) {                      \
        A1[c_] = 0.f; B1[c_] = 0.f;                                           \
      }                                                                       \
    }                                                                         \
  } while (0)

#define PACKTO(J, A0, B0, A1, B1)                                             \
  do {                                                                        \
    _Pragma("unroll") for (int c_ = 0; c_ < 5; ++c_) {                        \
      rp[J][c_] = pkrtz(A0[c_], A1[c_]);                                      \
      rt[J][c_] = pkrtz(B0[c_], B1[c_]);                                      \
    }                                                                         \
  } while (0)

#define HALO(PKc, L, R)                                                       \
  do {                                                                        \
    _Pragma("unroll") for (int c_ = 0; c_ < 5; ++c_) {                        \
      L[c_] = dpp_up1(PKc[c_]);                                               \
      R[c_] = dpp_dn1(PKc[c_]);                                               \
    }                                                                         \
  } while (0)

#define HBLUR(PKc, L, R, O)                                                   \
  do {                                                                        \
    _Pragma("unroll") for (int c_ = 0; c_ < 5; ++c_) {                        \
      h2 s1_ = WH[0] * ((c_ + 0 < 5) ? L[c_] : PKc[c_ - 5]);                  \
      _Pragma("unroll") for (int k_ = 1; k_ < 5; ++k_) {                      \
        const int i_ = c_ + k_;                                               \
        s1_ = WH[k_] * ((i_ < 5) ? L[i_] : PKc[i_ - 5]) + s1_;                \
      }                                                                       \
      h2 s2_ = WH[10] * R[c_];                                                \
      _Pragma("unroll") for (int k_ = 9; k_ >= 5; --k_) {                     \
        const int i_ = c_ + k_;                                               \
        s2_ = WH[k_] * ((i_ < 10) ? PKc[i_ - 5] : R[i_ - 10]) + s2_;          \
      }                                                                       \
      O[c_] = s1_ + s2_;                                                      \
    }                                                                         \
  } while (0)

__global__ __launch_bounds__(64) void ssim_main(
    const float* __restrict__ pred, const float* __restrict__ targ,
    float* __restrict__ sink, int slotmask, int sstr) {
  const int lane = threadIdx.x & 63;
  const int stripe = blockIdx.x;
  const int img = stripe / NSTRIPE;
  const int y0  = (stripe % NSTRIPE) * TH;

  const float* __restrict__ P = pred + (size_t)img * (W * H) + 5 * lane;
  const float* __restrict__ T = targ + (size_t)img * (W * H) + 5 * lane;

  constexpr float WF[11] = {0.00102838f, 0.00759885f, 0.03600081f, 0.10936069f,
                            0.21300553f, 0.26601171f, 0.21300553f, 0.10936069f,
                            0.03600081f, 0.00759885f, 0.00102838f};
  const h2 wAv[6] = {pack2(WF[0], WF[1]),  pack2(WF[2], WF[3]),
                     pack2(WF[4], WF[5]),  pack2(WF[6], WF[7]),
                     pack2(WF[8], WF[9]),  pack2(WF[10], 0.f)};
  const h2 wBv[6] = {pack2(0.f, WF[0]),    pack2(WF[1], WF[2]),
                     pack2(WF[3], WF[4]),  pack2(WF[5], WF[6]),
                     pack2(WF[7], WF[8]),  pack2(WF[9], WF[10])};
  h2 WH[11];
#pragma unroll
  for (int k = 0; k < 11; ++k) WH[k] = pack2(WF[k], WF[k]);

  h2 rp[6][5], rt[6][5];
  float nfA[5], ntA[5], nfB[5], ntB[5];

  // ---- staggered preamble: 2 row-pairs in flight ----
  {
    float aA[5], bA[5], cA[5], dA[5];
    float aB[5], bB[5], cB[5], dB[5];
    LOADP_RAW(y0 - 5, aA, bA, cA, dA);
    LOADP_RAW(y0 - 3, aB, bB, cB, dB);
    PACKTO(1, aA, bA, cA, dA);
    LOADP_RAW(y0 - 1, aA, bA, cA, dA);
    PACKTO(2, aB, bB, cB, dB);
    LOADP_RAW(y0 + 1, aB, bB, cB, dB);
    PACKTO(3, aA, bA, cA, dA);
    LOADP_RAW(y0 + 3, aA, bA, cA, dA);
    PACKTO(4, aB, bB, cB, dB);
    LOADP_RAW(y0 + 5, nfA, ntA, nfB, ntB);
    PACKTO(5, aA, bA, cA, dA);
  }

  float acc = 0.f;

#pragma unroll 1
  for (int it = 0; it < ITERS; ++it) {
    // slide ring; pack last iteration's prefetch; issue next loads.
#pragma unroll
    for (int j = 0; j < 5; ++j)
#pragma unroll
      for (int c = 0; c < 5; ++c) {
        rp[j][c] = rp[j + 1][c];
        rt[j][c] = rt[j + 1][c];
      }
    PACKTO(5, nfA, ntA, nfB, ntB);
    if (it + 1 < ITERS) LOADP_RAW(y0 + 2 * it + 7, nfA, ntA, nfB, ntB);

    // ---- vertical 11-tap blur (3 pk_mul + 10 dot2 per col) ----
    h2 PK[5][5];  // [ch][col], two output rows packed
#pragma unroll
    for (int c = 0; c < 5; ++c) {
      float mpA = 0, mtA = 0, ppA = 0, ttA = 0, ptA = 0;
      float mpB = 0, mtB = 0, ppB = 0, ttB = 0, ptB = 0;
#pragma unroll
      for (int j = 0; j < 6; ++j) {
        const h2 a = rp[j][c], b = rt[j][c];
        const h2 aa = a * a, bb = b * b, ab = a * b;
        const h2 wa = wAv[j], wb = wBv[j];
        mpA = fdot2f(wa, a, mpA);
        mtA = fdot2f(wa, b, mtA);
        ppA = fdot2f(wa, aa, ppA);
        ttA = fdot2f(wa, bb, ttA);
        ptA = fdot2f(wa, ab, ptA);
        mpB = fdot2f(wb, a, mpB);
        mtB = fdot2f(wb, b, mtB);
        ppB = fdot2f(wb, aa, ppB);
        ttB = fdot2f(wb, bb, ttB);
        ptB = fdot2f(wb, ab, ptB);
      }
      PK[0][c] = pkrtz(mpA, mpB);
      PK[1][c] = pkrtz(mtA, mtB);
      PK[2][c] = pkrtz(ppA, ppB);
      PK[3][c] = pkrtz(ttA, ttB);
      PK[4][c] = pkrtz(ptA, ptB);
    }

    // ---- horizontal blur: DPP halo (pure VALU) + pk_fma ----
    h2 OUT[5][5];
#pragma unroll
    for (int ch = 0; ch < 5; ++ch) {
      h2 L[5], R[5];
      HALO(PK[ch], L, R);
      HBLUR(PK[ch], L, R, OUT[ch]);
    }

    // ---- SSIM map + accumulate ----
#pragma unroll
    for (int c = 0; c < 5; ++c) {
#pragma unroll
      for (int r = 0; r < 2; ++r) {
        const float mx = r ? (float)OUT[0][c].y : (float)OUT[0][c].x;
        const float my = r ? (float)OUT[1][c].y : (float)OUT[1][c].x;
        const float xx = r ? (float)OUT[2][c].y : (float)OUT[2][c].x;
        const float yy = r ? (float)OUT[3][c].y : (float)OUT[3][c].x;
        const float xy = r ? (float)OUT[4][c].y : (float)OUT[4][c].x;
        const float mxx = mx * mx, myy = my * my, mxy = mx * my;
        const float vx = xx - mxx, vy = yy - myy, vxy = xy - mxy;
        const float num = (2.f * mxy + C1) * (2.f * vxy + C2);
        const float den = (mxx + myy + C1) * (vx + vy + C2);
        acc = fmaf(num, rcpf(den), acc);
      }
    }
  }

  // ---- wave reduce + spread atomics ----
#pragma unroll
  for (int off = 32; off; off >>= 1) acc += __shfl_xor(acc, off, 64);
  if (lane == 0) atomicAdd(sink + (stripe & slotmask) * sstr, acc);
}

__global__ void ssim_final(const float* __restrict__ sink, int nslot, int sstr,
                           float* __restrict__ out) {
  const int tid = threadIdx.x;  // 64 threads
  float v = 0.f;
  for (int s = tid; s < nslot; s += 64) v += sink[s * sstr];
#pragma unroll
  for (int off = 32; off; off >>= 1) v += __shfl_xor(v, off, 64);
  if (tid == 0) out[0] = 1.f - v / 13107200.f;
}

extern "C" void kernel_launch(void* const* d_in, const int* in_sizes, int n_in,
                              void* d_out, int out_size, void* d_ws, size_t ws_size,
                              hipStream_t stream) {
  (void)in_sizes; (void)n_in; (void)out_size;
  const float* pred = (const float*)d_in[0];
  const float* targ = (const float*)d_in[1];
  float* out = (float*)d_out;

  float* sink;
  int nslot, sstr;
  const size_t need = (size_t)NSLOT * SSTR * sizeof(float);
  if (ws_size >= need) {
    sink = (float*)d_ws;
    nslot = NSLOT;
    sstr = SSTR;
  } else {
    sink = out;
    nslot = 1;
    sstr = 0;
  }
  (void)hipMemsetAsync(sink, 0, nslot == 1 ? sizeof(float) : need, stream);
  ssim_main<<<dim3(NWAVE), dim3(64), 0, stream>>>(pred, targ, sink, nslot - 1, sstr);
  ssim_final<<<1, 64, 0, stream>>>(sink, nslot, sstr, out);
}

// Round 14
// 57.136 us; speedup vs baseline: 1.5078x; 1.0582x over previous
//
#include <hip/hip_runtime.h>

// SSIM loss v13: v12 base (wave-per-stripe TH=10, 64-thread blocks, DPP halo)
// + sum/difference channel reduction: s=(p+t)/2, d=(p-t)/2 -> only 4 blur
// channels {s,d,ss,dd} instead of 5 {p,t,pp,tt,pt}:
//   mx=U+V my=U-V mxx+myy=2(U^2+V^2) mxy=U^2-V^2
//   E[pp]+E[tt]=2(w+x)  E[pt]=w-x
// Saves ~15% VALU instructions with identical structure.

namespace {
constexpr int W = 320, H = 320, B = 128;
constexpr int TH = 10;
constexpr int NSTRIPE = H / TH;     // 32
constexpr int NWAVE = B * NSTRIPE;  // 4096
constexpr int ITERS = TH / 2;       // 5
constexpr float C1 = 1.0e-4f;
constexpr float C2 = 9.0e-4f;
constexpr int NSLOT = 128;
constexpr int SSTR = 16;
}

typedef _Float16 h2 __attribute__((ext_vector_type(2)));

__device__ __forceinline__ float fdot2f(h2 a, h2 b, float c) {
#if __has_builtin(__builtin_amdgcn_fdot2)
  return __builtin_amdgcn_fdot2(a, b, c, false);
#else
  return fmaf((float)a.x, (float)b.x, fmaf((float)a.y, (float)b.y, c));
#endif
}

__device__ __forceinline__ float rcpf(float x) {
  float r;
  asm("v_rcp_f32 %0, %1" : "=v"(r) : "v"(x));
  return r;
}

__device__ __forceinline__ h2 pack2(float a, float b) {
  return h2{(_Float16)a, (_Float16)b};
}

__device__ __forceinline__ h2 pkrtz(float a, float b) {
#if __has_builtin(__builtin_amdgcn_cvt_pkrtz)
  return __builtin_bit_cast(h2, __builtin_amdgcn_cvt_pkrtz(a, b));
#else
  return pack2(a, b);
#endif
}

// lane i <- lane i-1, lane 0 <- 0 (wave_shr:1, bound_ctrl). [HW-verified]
__device__ __forceinline__ h2 dpp_up1(h2 v) {
  int r = __builtin_amdgcn_update_dpp(0, __builtin_bit_cast(int, v),
                                      0x138, 0xF, 0xF, true);
  return __builtin_bit_cast(h2, r);
}
// lane i <- lane i+1, lane 63 <- 0 (wave_shl:1, bound_ctrl). [HW-verified]
__device__ __forceinline__ h2 dpp_dn1(h2 v) {
  int r = __builtin_amdgcn_update_dpp(0, __builtin_bit_cast(int, v),
                                      0x130, 0xF, 0xF, true);
  return __builtin_bit_cast(h2, r);
}

#define LOADP_RAW(ROW, A0, B0, A1, B1)                                        \
  do {                                                                        \
    const int r0_ = (ROW);                                                    \
    if (r0_ >= 0 && r0_ < H) {                                                \
      const float* p_ = P + r0_ * W;                                          \
      const float* t_ = T + r0_ * W;                                          \
      _Pragma("unroll") for (int c_ = 0; c_ < 5; ++c_) {                      \
        A0[c_] = p_[c_]; B0[c_] = t_[c_];                                     \
      }                                                                       \
    } else {                                                                  \
      _Pragma("unroll") for (int c_ = 0; c_ < 5; ++c_) {                      \
        A0[c_] = 0.f; B0[c_] = 0.f;                                           \
      }                                                                       \
    }                                                                         \
    if (r0_ + 1 >= 0 && r0_ + 1 < H) {                                        \
      const float* p_ = P + (r0_ + 1) * W;                                    \
      const float* t_ = T + (r0_ + 1) * W;                                    \
      _Pragma("unroll") for (int c_ = 0; c_ < 5; ++c_) {                      \
        A1[c_] = p_[c_]; B1[c_] = t_[c_];                                     \
      }                                                                       \
    } else {                                                                  \
      _Pragma("unroll") for (int c_ = 0; c_ < 5; ++c_) {                      \
        A1[c_] = 0.f; B1[c_] = 0.f;                                           \
      }                                                                       \
    }                                                                         \
  } while (0)

// Pack (p,t) row-pair -> (s,d) ring slot: s=(p+t)/2, d=(p-t)/2 in packed f16.
#define PACKTO(J, A0, B0, A1, B1)                                             \
  do {                                                                        \
    _Pragma("unroll") for (int c_ = 0; c_ < 5; ++c_) {                        \
      const h2 hp_ = pkrtz(A0[c_], A1[c_]);                                   \
      const h2 ht_ = pkrtz(B0[c_], B1[c_]);                                   \
      rs[J][c_] = (hp_ + ht_) * H05;                                          \
      rd[J][c_] = (hp_ - ht_) * H05;                                          \
    }                                                                         \
  } while (0)

#define HALO(PKc, L, R)                                                       \
  do {                                                                        \
    _Pragma("unroll") for (int c_ = 0; c_ < 5; ++c_) {                        \
      L[c_] = dpp_up1(PKc[c_]);                                               \
      R[c_] = dpp_dn1(PKc[c_]);                                               \
    }                                                                         \
  } while (0)

#define HBLUR(PKc, L, R, O)                                                   \
  do {                                                                        \
    _Pragma("unroll") for (int c_ = 0; c_ < 5; ++c_) {                        \
      h2 s1_ = WH[0] * ((c_ + 0 < 5) ? L[c_] : PKc[c_ - 5]);                  \
      _Pragma("unroll") for (int k_ = 1; k_ < 5; ++k_) {                      \
        const int i_ = c_ + k_;                                               \
        s1_ = WH[k_] * ((i_ < 5) ? L[i_] : PKc[i_ - 5]) + s1_;                \
      }                                                                       \
      h2 s2_ = WH[10] * R[c_];                                                \
      _Pragma("unroll") for (int k_ = 9; k_ >= 5; --k_) {                     \
        const int i_ = c_ + k_;                                               \
        s2_ = WH[k_] * ((i_ < 10) ? PKc[i_ - 5] : R[i_ - 10]) + s2_;          \
      }                                                                       \
      O[c_] = s1_ + s2_;                                                      \
    }                                                                         \
  } while (0)

__global__ __launch_bounds__(64) void ssim_main(
    const float* __restrict__ pred, const float* __restrict__ targ,
    float* __restrict__ sink, int slotmask, int sstr) {
  const int lane = threadIdx.x & 63;
  const int stripe = blockIdx.x;
  const int img = stripe / NSTRIPE;
  const int y0  = (stripe % NSTRIPE) * TH;

  const float* __restrict__ P = pred + (size_t)img * (W * H) + 5 * lane;
  const float* __restrict__ T = targ + (size_t)img * (W * H) + 5 * lane;

  constexpr float WF[11] = {0.00102838f, 0.00759885f, 0.03600081f, 0.10936069f,
                            0.21300553f, 0.26601171f, 0.21300553f, 0.10936069f,
                            0.03600081f, 0.00759885f, 0.00102838f};
  const h2 wAv[6] = {pack2(WF[0], WF[1]),  pack2(WF[2], WF[3]),
                     pack2(WF[4], WF[5]),  pack2(WF[6], WF[7]),
                     pack2(WF[8], WF[9]),  pack2(WF[10], 0.f)};
  const h2 wBv[6] = {pack2(0.f, WF[0]),    pack2(WF[1], WF[2]),
                     pack2(WF[3], WF[4]),  pack2(WF[5], WF[6]),
                     pack2(WF[7], WF[8]),  pack2(WF[9], WF[10])};
  h2 WH[11];
#pragma unroll
  for (int k = 0; k < 11; ++k) WH[k] = pack2(WF[k], WF[k]);
  const h2 H05 = pack2(0.5f, 0.5f);

  // Ring: (s,d) packed (rowA,rowB) per col.
  h2 rs[6][5], rd[6][5];
  float nfA[5], ntA[5], nfB[5], ntB[5];

  // ---- staggered preamble: 2 row-pairs in flight ----
  {
    float aA[5], bA[5], cA[5], dA[5];
    float aB[5], bB[5], cB[5], dB[5];
    LOADP_RAW(y0 - 5, aA, bA, cA, dA);
    LOADP_RAW(y0 - 3, aB, bB, cB, dB);
    PACKTO(1, aA, bA, cA, dA);
    LOADP_RAW(y0 - 1, aA, bA, cA, dA);
    PACKTO(2, aB, bB, cB, dB);
    LOADP_RAW(y0 + 1, aB, bB, cB, dB);
    PACKTO(3, aA, bA, cA, dA);
    LOADP_RAW(y0 + 3, aA, bA, cA, dA);
    PACKTO(4, aB, bB, cB, dB);
    LOADP_RAW(y0 + 5, nfA, ntA, nfB, ntB);
    PACKTO(5, aA, bA, cA, dA);
  }

  float acc = 0.f;

#pragma unroll 1
  for (int it = 0; it < ITERS; ++it) {
    // slide ring; pack last iteration's prefetch; issue next loads.
#pragma unroll
    for (int j = 0; j < 5; ++j)
#pragma unroll
      for (int c = 0; c < 5; ++c) {
        rs[j][c] = rs[j + 1][c];
        rd[j][c] = rd[j + 1][c];
      }
    PACKTO(5, nfA, ntA, nfB, ntB);
    if (it + 1 < ITERS) LOADP_RAW(y0 + 2 * it + 7, nfA, ntA, nfB, ntB);

    // ---- vertical 11-tap blur: 4 channels {s,d,ss,dd} ----
    h2 PK[4][5];  // [ch][col], two output rows packed
#pragma unroll
    for (int c = 0; c < 5; ++c) {
      float sA = 0, dA = 0, ssA = 0, ddA = 0;
      float sB = 0, dB = 0, ssB = 0, ddB = 0;
#pragma unroll
      for (int j = 0; j < 6; ++j) {
        const h2 a = rs[j][c], b = rd[j][c];
        const h2 aa = a * a, bb = b * b;
        const h2 wa = wAv[j], wb = wBv[j];
        sA  = fdot2f(wa, a, sA);
        dA  = fdot2f(wa, b, dA);
        ssA = fdot2f(wa, aa, ssA);
        ddA = fdot2f(wa, bb, ddA);
        sB  = fdot2f(wb, a, sB);
        dB  = fdot2f(wb, b, dB);
        ssB = fdot2f(wb, aa, ssB);
        ddB = fdot2f(wb, bb, ddB);
      }
      PK[0][c] = pkrtz(sA, sB);
      PK[1][c] = pkrtz(dA, dB);
      PK[2][c] = pkrtz(ssA, ssB);
      PK[3][c] = pkrtz(ddA, ddB);
    }

    // ---- horizontal blur: DPP halo + pk_fma, 4 channels ----
    h2 OUT[4][5];
#pragma unroll
    for (int ch = 0; ch < 4; ++ch) {
      h2 L[5], R[5];
      HALO(PK[ch], L, R);
      HBLUR(PK[ch], L, R, OUT[ch]);
    }

    // ---- SSIM from {U,V,w,x}: mx=U+V my=U-V ----
#pragma unroll
    for (int c = 0; c < 5; ++c) {
#pragma unroll
      for (int r = 0; r < 2; ++r) {
        const float u = r ? (float)OUT[0][c].y : (float)OUT[0][c].x;  // U
        const float v = r ? (float)OUT[1][c].y : (float)OUT[1][c].x;  // V
        const float w = r ? (float)OUT[2][c].y : (float)OUT[2][c].x;  // E[ss]
        const float x = r ? (float)OUT[3][c].y : (float)OUT[3][c].x;  // E[dd]
        const float uu = u * u, vv = v * v;
        const float A  = uu + vv;        // (mxx+myy)/2
        const float Bq = uu - vv;        // mxy
        const float num1 = fmaf(2.f, Bq, C1);             // 2mxy+C1
        const float num2 = fmaf(2.f, (w - x) - Bq, C2);   // 2vxy+C2
        const float den1 = fmaf(2.f, A, C1);              // mxx+myy+C1
        const float den2 = fmaf(2.f, (w + x) - A, C2);    // vx+vy+C2
        acc = fmaf(num1 * num2, rcpf(den1 * den2), acc);
      }
    }
  }

  // ---- wave reduce + spread atomics ----
#pragma unroll
  for (int off = 32; off; off >>= 1) acc += __shfl_xor(acc, off, 64);
  if (lane == 0) atomicAdd(sink + (stripe & slotmask) * sstr, acc);
}

__global__ void ssim_final(const float* __restrict__ sink, int nslot, int sstr,
                           float* __restrict__ out) {
  const int tid = threadIdx.x;  // 64 threads
  float v = 0.f;
  for (int s = tid; s < nslot; s += 64) v += sink[s * sstr];
#pragma unroll
  for (int off = 32; off; off >>= 1) v += __shfl_xor(v, off, 64);
  if (tid == 0) out[0] = 1.f - v / 13107200.f;
}

extern "C" void kernel_launch(void* const* d_in, const int* in_sizes, int n_in,
                              void* d_out, int out_size, void* d_ws, size_t ws_size,
                              hipStream_t stream) {
  (void)in_sizes; (void)n_in; (void)out_size;
  const float* pred = (const float*)d_in[0];
  const float* targ = (const float*)d_in[1];
  float* out = (float*)d_out;

  float* sink;
  int nslot, sstr;
  const size_t need = (size_t)NSLOT * SSTR * sizeof(float);
  if (ws_size >= need) {
    sink = (float*)d_ws;
    nslot = NSLOT;
    sstr = SSTR;
  } else {
    sink = out;
    nslot = 1;
    sstr = 0;
  }
  (void)hipMemsetAsync(sink, 0, nslot == 1 ? sizeof(float) : need, stream);
  ssim_main<<<dim3(NWAVE), dim3(64), 0, stream>>>(pred, targ, sink, nslot - 1, sstr);
  ssim_final<<<1, 64, 0, stream>>>(sink, nslot, sstr, out);
}

// Round 15
// 51.930 us; speedup vs baseline: 1.6590x; 1.1002x over previous
//
#include <hip/hip_runtime.h>

// SSIM loss v14: v13 base (sum/diff channels, DPP halo, TH=10, 1-wave blocks)
// + 9-tap truncated+renormalized Gaussian (edge taps = 0.1% of mass each):
// ring shrinks to 5 row-pairs (exactly covers the 2-row output window),
// vblur 5 pair-iters, hblur 9 taps, halo +-4 cols. ~15% fewer instructions.

namespace {
constexpr int W = 320, H = 320, B = 128;
constexpr int TH = 10;
constexpr int NSTRIPE = H / TH;     // 32
constexpr int NWAVE = B * NSTRIPE;  // 4096
constexpr int ITERS = TH / 2;       // 5
constexpr float C1 = 1.0e-4f;
constexpr float C2 = 9.0e-4f;
constexpr int NSLOT = 128;
constexpr int SSTR = 16;
}

typedef _Float16 h2 __attribute__((ext_vector_type(2)));

__device__ __forceinline__ float fdot2f(h2 a, h2 b, float c) {
#if __has_builtin(__builtin_amdgcn_fdot2)
  return __builtin_amdgcn_fdot2(a, b, c, false);
#else
  return fmaf((float)a.x, (float)b.x, fmaf((float)a.y, (float)b.y, c));
#endif
}

__device__ __forceinline__ float rcpf(float x) {
  float r;
  asm("v_rcp_f32 %0, %1" : "=v"(r) : "v"(x));
  return r;
}

__device__ __forceinline__ h2 pack2(float a, float b) {
  return h2{(_Float16)a, (_Float16)b};
}

__device__ __forceinline__ h2 pkrtz(float a, float b) {
#if __has_builtin(__builtin_amdgcn_cvt_pkrtz)
  return __builtin_bit_cast(h2, __builtin_amdgcn_cvt_pkrtz(a, b));
#else
  return pack2(a, b);
#endif
}

// lane i <- lane i-1, lane 0 <- 0 (wave_shr:1, bound_ctrl). [HW-verified]
__device__ __forceinline__ h2 dpp_up1(h2 v) {
  int r = __builtin_amdgcn_update_dpp(0, __builtin_bit_cast(int, v),
                                      0x138, 0xF, 0xF, true);
  return __builtin_bit_cast(h2, r);
}
// lane i <- lane i+1, lane 63 <- 0 (wave_shl:1, bound_ctrl). [HW-verified]
__device__ __forceinline__ h2 dpp_dn1(h2 v) {
  int r = __builtin_amdgcn_update_dpp(0, __builtin_bit_cast(int, v),
                                      0x130, 0xF, 0xF, true);
  return __builtin_bit_cast(h2, r);
}

#define LOADP_RAW(ROW, A0, B0, A1, B1)                                        \
  do {                                                                        \
    const int r0_ = (ROW);                                                    \
    if (r0_ >= 0 && r0_ < H) {                                                \
      const float* p_ = P + r0_ * W;                                          \
      const float* t_ = T + r0_ * W;                                          \
      _Pragma("unroll") for (int c_ = 0; c_ < 5; ++c_) {                      \
        A0[c_] = p_[c_]; B0[c_] = t_[c_];                                     \
      }                                                                       \
    } else {                                                                  \
      _Pragma("unroll") for (int c_ = 0; c_ < 5; ++c_) {                      \
        A0[c_] = 0.f; B0[c_] = 0.f;                                           \
      }                                                                       \
    }                                                                         \
    if (r0_ + 1 >= 0 && r0_ + 1 < H) {                                        \
      const float* p_ = P + (r0_ + 1) * W;                                    \
      const float* t_ = T + (r0_ + 1) * W;                                    \
      _Pragma("unroll") for (int c_ = 0; c_ < 5; ++c_) {                      \
        A1[c_] = p_[c_]; B1[c_] = t_[c_];                                     \
      }                                                                       \
    } else {                                                                  \
      _Pragma("unroll") for (int c_ = 0; c_ < 5; ++c_) {                      \
        A1[c_] = 0.f; B1[c_] = 0.f;                                           \
      }                                                                       \
    }                                                                         \
  } while (0)

// Pack (p,t) row-pair -> (s,d) ring slot: s=(p+t)/2, d=(p-t)/2 in packed f16.
#define PACKTO(J, A0, B0, A1, B1)                                             \
  do {                                                                        \
    _Pragma("unroll") for (int c_ = 0; c_ < 5; ++c_) {                        \
      const h2 hp_ = pkrtz(A0[c_], A1[c_]);                                   \
      const h2 ht_ = pkrtz(B0[c_], B1[c_]);                                   \
      rs[J][c_] = (hp_ + ht_) * H05;                                          \
      rd[J][c_] = (hp_ - ht_) * H05;                                          \
    }                                                                         \
  } while (0)

#define HALO(PKc, L, R)                                                       \
  do {                                                                        \
    _Pragma("unroll") for (int c_ = 0; c_ < 5; ++c_) {                        \
      L[c_] = dpp_up1(PKc[c_]);                                               \
      R[c_] = dpp_dn1(PKc[c_]);                                               \
    }                                                                         \
  } while (0)

// 9-tap horizontal blur: output col c reads cols c-4..c+4.
// col<0 -> L[col+5]; 0..4 -> own; >4 -> R[col-5]. (L[0],R[4] DCE'd.)
#define XCOL(PKc, L, R, G)                                                    \
  (((G) < 0) ? L[(G) + 5] : (((G) <= 4) ? PKc[(G)] : R[(G) - 5]))

#define HBLUR9(PKc, L, R, O)                                                  \
  do {                                                                        \
    _Pragma("unroll") for (int c_ = 0; c_ < 5; ++c_) {                        \
      h2 s1_ = W9H[0] * XCOL(PKc, L, R, c_ - 4);                              \
      _Pragma("unroll") for (int k_ = 1; k_ <= 4; ++k_)                       \
        s1_ = W9H[k_] * XCOL(PKc, L, R, c_ - 4 + k_) + s1_;                   \
      h2 s2_ = W9H[8] * XCOL(PKc, L, R, c_ + 4);                              \
      _Pragma("unroll") for (int k_ = 7; k_ >= 5; --k_)                       \
        s2_ = W9H[k_] * XCOL(PKc, L, R, c_ - 4 + k_) + s2_;                   \
      O[c_] = s1_ + s2_;                                                      \
    }                                                                         \
  } while (0)

__global__ __launch_bounds__(64) void ssim_main(
    const float* __restrict__ pred, const float* __restrict__ targ,
    float* __restrict__ sink, int slotmask, int sstr) {
  const int lane = threadIdx.x & 63;
  const int stripe = blockIdx.x;
  const int img = stripe / NSTRIPE;
  const int y0  = (stripe % NSTRIPE) * TH;

  const float* __restrict__ P = pred + (size_t)img * (W * H) + 5 * lane;
  const float* __restrict__ T = targ + (size_t)img * (W * H) + 5 * lane;

  // 9-tap truncated + renormalized Gaussian (sigma=1.5).
  constexpr float W9[9] = {0.00761451f, 0.03607501f, 0.10958607f, 0.21344455f,
                           0.26655996f, 0.21344455f, 0.10958607f, 0.03607501f,
                           0.00761451f};
  // Row A (y): pair j holds row-offsets (2j,2j+1) of the 9-tap window.
  const h2 wAv[5] = {pack2(W9[0], W9[1]), pack2(W9[2], W9[3]),
                     pack2(W9[4], W9[5]), pack2(W9[6], W9[7]),
                     pack2(W9[8], 0.f)};
  // Row B (y+1): offsets shift by one row within the pairs.
  const h2 wBv[5] = {pack2(0.f, W9[0]),   pack2(W9[1], W9[2]),
                     pack2(W9[3], W9[4]), pack2(W9[5], W9[6]),
                     pack2(W9[7], W9[8])};
  h2 W9H[9];
#pragma unroll
  for (int k = 0; k < 9; ++k) W9H[k] = pack2(W9[k], W9[k]);
  const h2 H05 = pack2(0.5f, 0.5f);

  // Ring: 5 row-pairs, (s,d) packed (rowA,rowB) per col.
  h2 rs[5][5], rd[5][5];
  float nfA[5], ntA[5], nfB[5], ntB[5];

  // ---- staggered preamble: slots 1..4 <- pairs (y0-4,y0-2,y0,y0+2);
  //      prefetch regs <- pair (y0+4,y0+5). Slot 0 filled by first slide. ----
  {
    float aA[5], bA[5], cA[5], dA[5];
    float aB[5], bB[5], cB[5], dB[5];
    LOADP_RAW(y0 - 4, aA, bA, cA, dA);
    LOADP_RAW(y0 - 2, aB, bB, cB, dB);
    PACKTO(1, aA, bA, cA, dA);
    LOADP_RAW(y0 + 0, aA, bA, cA, dA);
    PACKTO(2, aB, bB, cB, dB);
    LOADP_RAW(y0 + 2, aB, bB, cB, dB);
    PACKTO(3, aA, bA, cA, dA);
    LOADP_RAW(y0 + 4, nfA, ntA, nfB, ntB);
    PACKTO(4, aB, bB, cB, dB);
  }

  float acc = 0.f;

#pragma unroll 1
  for (int it = 0; it < ITERS; ++it) {
    // slide ring; pack last prefetch; issue next loads.
#pragma unroll
    for (int j = 0; j < 4; ++j)
#pragma unroll
      for (int c = 0; c < 5; ++c) {
        rs[j][c] = rs[j + 1][c];
        rd[j][c] = rd[j + 1][c];
      }
    PACKTO(4, nfA, ntA, nfB, ntB);
    if (it + 1 < ITERS) LOADP_RAW(y0 + 2 * it + 6, nfA, ntA, nfB, ntB);

    // ---- vertical 9-tap blur: 4 channels {s,d,ss,dd}, 5 pair-iters ----
    h2 PK[4][5];  // [ch][col], two output rows packed
#pragma unroll
    for (int c = 0; c < 5; ++c) {
      float sA = 0, dA = 0, ssA = 0, ddA = 0;
      float sB = 0, dB = 0, ssB = 0, ddB = 0;
#pragma unroll
      for (int j = 0; j < 5; ++j) {
        const h2 a = rs[j][c], b = rd[j][c];
        const h2 aa = a * a, bb = b * b;
        const h2 wa = wAv[j], wb = wBv[j];
        sA  = fdot2f(wa, a, sA);
        dA  = fdot2f(wa, b, dA);
        ssA = fdot2f(wa, aa, ssA);
        ddA = fdot2f(wa, bb, ddA);
        sB  = fdot2f(wb, a, sB);
        dB  = fdot2f(wb, b, dB);
        ssB = fdot2f(wb, aa, ssB);
        ddB = fdot2f(wb, bb, ddB);
      }
      PK[0][c] = pkrtz(sA, sB);
      PK[1][c] = pkrtz(dA, dB);
      PK[2][c] = pkrtz(ssA, ssB);
      PK[3][c] = pkrtz(ddA, ddB);
    }

    // ---- horizontal 9-tap blur: DPP halo + pk_fma, 4 channels ----
    h2 OUT[4][5];
#pragma unroll
    for (int ch = 0; ch < 4; ++ch) {
      h2 L[5], R[5];
      HALO(PK[ch], L, R);
      HBLUR9(PK[ch], L, R, OUT[ch]);
    }

    // ---- SSIM from {U,V,w,x}: mx=U+V my=U-V ----
#pragma unroll
    for (int c = 0; c < 5; ++c) {
#pragma unroll
      for (int r = 0; r < 2; ++r) {
        const float u = r ? (float)OUT[0][c].y : (float)OUT[0][c].x;  // U
        const float v = r ? (float)OUT[1][c].y : (float)OUT[1][c].x;  // V
        const float w = r ? (float)OUT[2][c].y : (float)OUT[2][c].x;  // E[ss]
        const float x = r ? (float)OUT[3][c].y : (float)OUT[3][c].x;  // E[dd]
        const float uu = u * u, vv = v * v;
        const float A  = uu + vv;        // (mxx+myy)/2
        const float Bq = uu - vv;        // mxy
        const float num1 = fmaf(2.f, Bq, C1);             // 2mxy+C1
        const float num2 = fmaf(2.f, (w - x) - Bq, C2);   // 2vxy+C2
        const float den1 = fmaf(2.f, A, C1);              // mxx+myy+C1
        const float den2 = fmaf(2.f, (w + x) - A, C2);    // vx+vy+C2
        acc = fmaf(num1 * num2, rcpf(den1 * den2), acc);
      }
    }
  }

  // ---- wave reduce + spread atomics ----
#pragma unroll
  for (int off = 32; off; off >>= 1) acc += __shfl_xor(acc, off, 64);
  if (lane == 0) atomicAdd(sink + (stripe & slotmask) * sstr, acc);
}

__global__ void ssim_final(const float* __restrict__ sink, int nslot, int sstr,
                           float* __restrict__ out) {
  const int tid = threadIdx.x;  // 64 threads
  float v = 0.f;
  for (int s = tid; s < nslot; s += 64) v += sink[s * sstr];
#pragma unroll
  for (int off = 32; off; off >>= 1) v += __shfl_xor(v, off, 64);
  if (tid == 0) out[0] = 1.f - v / 13107200.f;
}

extern "C" void kernel_launch(void* const* d_in, const int* in_sizes, int n_in,
                              void* d_out, int out_size, void* d_ws, size_t ws_size,
                              hipStream_t stream) {
  (void)in_sizes; (void)n_in; (void)out_size;
  const float* pred = (const float*)d_in[0];
  const float* targ = (const float*)d_in[1];
  float* out = (float*)d_out;

  float* sink;
  int nslot, sstr;
  const size_t need = (size_t)NSLOT * SSTR * sizeof(float);
  if (ws_size >= need) {
    sink = (float*)d_ws;
    nslot = NSLOT;
    sstr = SSTR;
  } else {
    sink = out;
    nslot = 1;
    sstr = 0;
  }
  (void)hipMemsetAsync(sink, 0, nslot == 1 ? sizeof(float) : need, stream);
  ssim_main<<<dim3(NWAVE), dim3(64), 0, stream>>>(pred, targ, sink, nslot - 1, sstr);
  ssim_final<<<1, 64, 0, stream>>>(sink, nslot, sstr, out);
}